// Round 3
// baseline (228.464 us; speedup 1.0000x reference)
//
#include <hip/hip_runtime.h>

// Cascaded convex upsampling (SEAFLOW3DP), fused in PAIRS of x2 stages:
//   K1: x16 -> x8 -> x4   (mask16 at coarse, mask8 at mid)  -> ws
//   K2: x4  -> x2 -> x1   (mask4  at coarse, mask2 at mid)  -> d_out
//
// Tile = TH x TW MID-level pixels per block (one thread per mid "parent").
// TW=32 so each wave row reads 32 consecutive floats of the big mask.
//
// Phase 0: ASYNC-stage this block's 36 x NT phase-2 mask values into LDS
//          via global_load_lds (hardware async, zero VGPR cost, cannot be
//          sunk by the compiler -- round-2's register prefetch was defeated
//          by VGPR pressure, VGPR_Count=44 proved it). Latency hides under
//          phase 1; __syncthreads' vmcnt(0) drain publishes it.
// Phase 1: compute the mid-level field on (TH+2)x(TW+2) incl. 1-px halo,
//          store to LDS (row stride TW+3 -> max 2-way bank alias, free).
//          Out-of-image halo = 0 == the zero padding the 2nd unfold needs.
// Phase 2: exp the staged mask (sme[c][tid]: consecutive lanes -> 2-way,
//          free), 27 LDS taps, 144 FMA -> 2x2 fine outputs x 3 channels.
//
// Softmax semantics: zero-padded taps contribute 0 to the numerator but
// keep their weight in the denominator -> zero the TAP, not the weight.
// Flow premul=2 applied per stage, dz premul=1.

#define NB 4

typedef const __attribute__((address_space(1))) void gas_void;
typedef __attribute__((address_space(3))) void las_void;

template <int Hc, int Wc, int TH, int TW, int NT>
__global__ __launch_bounds__(NT) void fused_up4(
    const float* __restrict__ flowIn,  // (NB,2,Hc,Wc)
    const float* __restrict__ dzIn,    // (NB,1,Hc,Wc)
    const float* __restrict__ maskA,   // (NB,36,Hc,Wc)      coarse-level mask
    const float* __restrict__ maskB,   // (NB,36,2Hc,2Wc)    mid-level mask
    float* __restrict__ flowOut,       // ch0 at n*flowOutBS, ch1 at +4Hc*4Wc
    float* __restrict__ dzOut,         // at n*dzOutBS
    int flowOutBS, int dzOutBS)
{
    constexpr int HWc = Hc * Wc;
    constexpr int Hm = 2 * Hc, Wm = 2 * Wc;
    constexpr int HWm = Hm * Wm;
    constexpr int W4 = 4 * Wc;
    constexpr int TBX = Wm / TW, TBY = Hm / TH;
    constexpr int RH = TH + 2, RW = TW + 2;
    constexpr int NR = RH * RW;

    __shared__ float sme[36][NT];                 // staged phase-2 mask
    __shared__ float smx[RH][RW + 1], smy[RH][RW + 1], smz[RH][RW + 1];

    int b = blockIdx.x;
    int tX = b % TBX;
    int t2 = b / TBX;
    int tY = t2 % TBY;
    int n  = t2 / TBY;

    int m0y = tY * TH, m0x = tX * TW;    // mid tile origin

    int tid = threadIdx.x;
    int px = tid % TW, py = tid / TW;
    int pmy = m0y + py, pmx = m0x + px;  // this thread's mid parent (in range)
    int wv = tid >> 6;                   // wave id (LDS dest base is wave-uniform)

    // ---- phase 0: async global->LDS stage of the 36 phase-2 mask taps ----
    const float* mbp = maskB + (size_t)n * 36 * HWm + (size_t)pmy * Wm + pmx;
#pragma unroll
    for (int c = 0; c < 36; ++c) {
        __builtin_amdgcn_global_load_lds(
            (gas_void*)(mbp + (size_t)c * HWm),
            (las_void*)&sme[c][wv * 64], 4, 0, 0);
    }

    // ---------------- phase 1: mid tile (TH+2 x TW+2 incl. halo) ----------
    const float* fb = flowIn + (size_t)n * 2 * HWc;
    const float* db = dzIn   + (size_t)n * HWc;
    const float* mA = maskA  + (size_t)n * 36 * HWc;

#pragma unroll
    for (int it = 0; it < (NR + NT - 1) / NT; ++it) {
        int i = it * NT + tid;
        if (i < NR) {
            int ym = i / RW, xm = i % RW;
            int my = m0y - 1 + ym, mx = m0x - 1 + xm;
            float vx = 0.f, vy = 0.f, vz = 0.f;
            if ((unsigned)my < (unsigned)Hm && (unsigned)mx < (unsigned)Wm) {
                int pcy = my >> 1, pcx = mx >> 1;        // coarse parent
                int q = (my & 1) * 2 + (mx & 1);         // quadrant
                const float* ma = mA + (size_t)pcy * Wc + pcx;
                float e9[9];
#pragma unroll
                for (int k = 0; k < 9; ++k)
                    e9[k] = __expf(ma[(size_t)(k * 4 + q) * HWc]);
                float s = 0.f, ax = 0.f, ay = 0.f, az = 0.f;
#pragma unroll
                for (int kh = 0; kh < 3; ++kh) {
                    int hh = pcy + kh - 1;
                    bool vh = (unsigned)hh < (unsigned)Hc;
                    int hcl = min(max(hh, 0), Hc - 1);
#pragma unroll
                    for (int kw = 0; kw < 3; ++kw) {
                        int ww = pcx + kw - 1;
                        bool v = vh && ((unsigned)ww < (unsigned)Wc);
                        int wcl = min(max(ww, 0), Wc - 1);
                        int o = hcl * Wc + wcl;
                        int k = kh * 3 + kw;
                        float x = fb[o], y = fb[HWc + o], z = db[o];
                        x = v ? x : 0.f; y = v ? y : 0.f; z = v ? z : 0.f;
                        float w = e9[k];
                        s  += w;
                        ax += w * x;
                        ay += w * y;
                        az += w * z;
                    }
                }
                float inv = __builtin_amdgcn_rcpf(s);
                float fs = 2.0f * inv;   // per-stage flow premul
                vx = ax * fs; vy = ay * fs; vz = az * inv;
            }
            smx[ym][xm] = vx; smy[ym][xm] = vy; smz[ym][xm] = vz;
        }
    }

    __syncthreads();   // drains vmcnt(0): staged mask + field tile published

    // ------------- phase 2: one mid-parent per thread -------------
    float e[36];
#pragma unroll
    for (int c = 0; c < 36; ++c) e[c] = __expf(sme[c][tid]);

    float tx[9], ty[9], tz[9];
#pragma unroll
    for (int kh = 0; kh < 3; ++kh)
#pragma unroll
        for (int kw = 0; kw < 3; ++kw) {
            int k = kh * 3 + kw;
            tx[k] = smx[py + kh][px + kw];
            ty[k] = smy[py + kh][px + kw];
            tz[k] = smz[py + kh][px + kw];
        }

    float* fo0 = flowOut + (size_t)n * flowOutBS;
    float* fo1 = fo0 + (size_t)(4 * Hc) * W4;           // channel stride
    float* dzo = dzOut + (size_t)n * dzOutBS;

#pragma unroll
    for (int sy = 0; sy < 2; ++sy) {
        float2 rx, ry, rz;
#pragma unroll
        for (int sx = 0; sx < 2; ++sx) {
            int q = sy * 2 + sx;
            float s = 0.f, ax = 0.f, ay = 0.f, az = 0.f;
#pragma unroll
            for (int k = 0; k < 9; ++k) {
                float w = e[k * 4 + q];
                s  += w;
                ax += w * tx[k];
                ay += w * ty[k];
                az += w * tz[k];
            }
            float inv = __builtin_amdgcn_rcpf(s);
            float fs = 2.0f * inv;
            if (sx == 0) { rx.x = ax * fs; ry.x = ay * fs; rz.x = az * inv; }
            else         { rx.y = ax * fs; ry.y = ay * fs; rz.y = az * inv; }
        }
        size_t oo = (size_t)(2 * pmy + sy) * W4 + 2 * pmx;
        *(float2*)(fo0 + oo) = rx;
        *(float2*)(fo1 + oo) = ry;
        *(float2*)(dzo + oo) = rz;
    }
}

extern "C" void kernel_launch(void* const* d_in, const int* in_sizes, int n_in,
                              void* d_out, int out_size, void* d_ws, size_t ws_size,
                              hipStream_t stream) {
    const float* flow16 = (const float*)d_in[0];  // (4,2,48,64)
    const float* dz16   = (const float*)d_in[1];  // (4,1,48,64)
    const float* mask16 = (const float*)d_in[2];  // (4,36,48,64)
    const float* mask8  = (const float*)d_in[3];  // (4,36,96,128)
    const float* mask4  = (const float*)d_in[4];  // (4,36,192,256)
    const float* mask2  = (const float*)d_in[5];  // (4,36,384,512)

    float* ws = (float*)d_ws;
    float* flowB = ws;                            // (4,2,192,256)
    float* dzB   = flowB + 4 * 2 * 192 * 256;     // (4,1,192,256)

    float* out = (float*)d_out;                   // (4,3,768,1024)
    const int HW1 = 768 * 1024;
    const int HW4 = 192 * 256;

    // K1: x16 -> x4. mid = 96x128, tile 4x32 -> 4*24*4 = 384 blocks of 128.
    hipLaunchKernelGGL((fused_up4<48, 64, 4, 32, 128>),
                       dim3(NB * (96 / 4) * (128 / 32)), dim3(128), 0, stream,
                       flow16, dz16, mask16, mask8, flowB, dzB, 2 * HW4, HW4);
    // K2: x4 -> x1. mid = 384x512, tile 4x32 -> 4*96*16 = 6144 blocks of 128.
    hipLaunchKernelGGL((fused_up4<192, 256, 4, 32, 128>),
                       dim3(NB * (384 / 4) * (512 / 32)), dim3(128), 0, stream,
                       flowB, dzB, mask4, mask2, out, out + 2 * HW1, 3 * HW1, 3 * HW1);
}

// Round 4
// 226.782 us; speedup vs baseline: 1.0074x; 1.0074x over previous
//
#include <hip/hip_runtime.h>

// Cascaded convex upsampling (SEAFLOW3DP), fused in PAIRS of x2 stages:
//   K1: x16 -> x8 -> x4   (mask16 at coarse, mask8 at mid)  -> ws
//   K2: x4  -> x2 -> x1   (mask4  at coarse, mask2 at mid)  -> d_out
//
// Block = TH x TW MID-level tile.
// Phase 1: one thread per COARSE parent (CH=TH/2+2 x CW=TW/2+2 incl. 1-px
//          coarse halo). All 36 mask + 27 field loads are lane-contiguous
//          (4B stride) -> perfect coalescing. Each thread computes its 2x2
//          mid quadrants and writes aligned float2 to LDS. Out-of-image
//          parents write 0 (== the zero padding the 2nd unfold needs).
// Phase 2: one thread per 4 CONSECUTIVE mid parents. 36 mask loads become
//          2x18 float4 (1KB/wave-instr, 288B/thread in flight per batch ->
//          latency hidden by ILP, not occupancy). Taps: 2 aligned b128 LDS
//          reads per row per field (conflict-free). Stores: 2x float4 per
//          row per channel (32B/lane contiguous).
//
// Softmax semantics: zero-padded taps contribute 0 to the numerator but
// keep their weight in the denominator -> zero the TAP, not the weight.
// Flow premul=2 per stage, dz premul=1.

#define NB 4

__device__ __forceinline__ float f4get(const float4& v, int i) {
    switch (i) { case 0: return v.x; case 1: return v.y; case 2: return v.z; default: return v.w; }
}

template <int Hc, int Wc, int TH, int TW>
__global__ __launch_bounds__(TH * TW / 4) void fused_up4(
    const float* __restrict__ flowIn,  // (NB,2,Hc,Wc)
    const float* __restrict__ dzIn,    // (NB,1,Hc,Wc)
    const float* __restrict__ maskA,   // (NB,36,Hc,Wc)
    const float* __restrict__ maskB,   // (NB,36,2Hc,2Wc)
    float* __restrict__ flowOut,       // ch0 at n*flowOutBS, ch1 at +4Hc*4Wc
    float* __restrict__ dzOut,         // at n*dzOutBS
    int flowOutBS, int dzOutBS)
{
    constexpr int NT  = TH * TW / 4;
    constexpr int HWc = Hc * Wc;
    constexpr int Hm = 2 * Hc, Wm = 2 * Wc;
    constexpr int HWm = Hm * Wm;
    constexpr int W4 = 4 * Wc;
    constexpr int TBX = Wm / TW, TBY = Hm / TH;
    constexpr int RH = TH + 2, WP = TW + 4;         // LDS field tile (rows x cols)
    constexpr int CH = TH / 2 + 2, CW = TW / 2 + 2; // coarse tile incl. halo
    constexpr int NS = CH * CW;
    constexpr int UX = TW / 4;                      // phase-2 threads per row

    __shared__ __align__(16) float smx[RH][WP], smy[RH][WP], smz[RH][WP];

    int b = blockIdx.x;
    int tX = b % TBX;
    int t2 = b / TBX;
    int tY = t2 % TBY;
    int n  = t2 / TBY;

    int m0y = tY * TH, m0x = tX * TW;         // mid tile origin
    int cy0 = m0y / 2 - 1, cx0 = m0x / 2 - 1; // coarse tile origin (incl. halo)

    int tid = threadIdx.x;

    const float* fb = flowIn + (size_t)n * 2 * HWc;
    const float* db = dzIn   + (size_t)n * HWc;
    const float* mA = maskA  + (size_t)n * 36 * HWc;

    // ---------------- phase 1: one thread per coarse parent ----------------
#pragma unroll
    for (int it = 0; it < (NS + NT - 1) / NT; ++it) {
        int s = it * NT + tid;
        if (s < NS) {
            int lc = s % CW, lr = s / CW;
            int pcy = cy0 + lr, pcx = cx0 + lc;
            float vx[2][2] = {{0.f, 0.f}, {0.f, 0.f}};
            float vy[2][2] = {{0.f, 0.f}, {0.f, 0.f}};
            float vz[2][2] = {{0.f, 0.f}, {0.f, 0.f}};
            if ((unsigned)pcy < (unsigned)Hc && (unsigned)pcx < (unsigned)Wc) {
                const float* ma = mA + (size_t)pcy * Wc + pcx;
                float e[36];
#pragma unroll
                for (int c = 0; c < 36; ++c) e[c] = ma[(size_t)c * HWc];

                float tx[9], ty[9], tz[9];
#pragma unroll
                for (int kh = 0; kh < 3; ++kh) {
                    int hh = pcy + kh - 1;
                    bool vh = (unsigned)hh < (unsigned)Hc;
                    int hcl = min(max(hh, 0), Hc - 1);
#pragma unroll
                    for (int kw = 0; kw < 3; ++kw) {
                        int ww = pcx + kw - 1;
                        bool v = vh && ((unsigned)ww < (unsigned)Wc);
                        int wcl = min(max(ww, 0), Wc - 1);
                        int o = hcl * Wc + wcl;
                        int k = kh * 3 + kw;
                        float x = fb[o], y = fb[HWc + o], z = db[o];
                        tx[k] = v ? x : 0.f;
                        ty[k] = v ? y : 0.f;
                        tz[k] = v ? z : 0.f;
                    }
                }
#pragma unroll
                for (int c = 0; c < 36; ++c) e[c] = __expf(e[c]);

#pragma unroll
                for (int dy = 0; dy < 2; ++dy)
#pragma unroll
                    for (int dx = 0; dx < 2; ++dx) {
                        int q = dy * 2 + dx;
                        float sum = 0.f, ax = 0.f, ay = 0.f, az = 0.f;
#pragma unroll
                        for (int k = 0; k < 9; ++k) {
                            float w = e[k * 4 + q];
                            sum += w;
                            ax += w * tx[k];
                            ay += w * ty[k];
                            az += w * tz[k];
                        }
                        float inv = __builtin_amdgcn_rcpf(sum);
                        float fs = 2.0f * inv;   // per-stage flow premul
                        vx[dy][dx] = ax * fs;
                        vy[dy][dx] = ay * fs;
                        vz[dy][dx] = az * inv;
                    }
            }
            // write 2x2 mid quadrants as aligned float2 rows (skip rows
            // outside the LDS tile; zero rows cover the out-of-image halo)
#pragma unroll
            for (int dy = 0; dy < 2; ++dy) {
                int ar = 2 * lr + dy - 1;
                if (ar >= 0 && ar < RH) {
                    int ac = 2 * lc;
                    *(float2*)&smx[ar][ac] = make_float2(vx[dy][0], vx[dy][1]);
                    *(float2*)&smy[ar][ac] = make_float2(vy[dy][0], vy[dy][1]);
                    *(float2*)&smz[ar][ac] = make_float2(vz[dy][0], vz[dy][1]);
                }
            }
        }
    }
    __syncthreads();

    // ------------- phase 2: one thread per 4 consecutive mid parents -------
    int u  = tid % UX;
    int py = tid / UX;
    int pmy = m0y + py;

    const float* mb = maskB + (size_t)n * 36 * HWm + (size_t)pmy * Wm + (m0x + 4 * u);

    float* fo0 = flowOut + (size_t)n * flowOutBS;
    float* fo1 = fo0 + (size_t)(4 * Hc) * W4;      // channel stride = H1*W1
    float* dzo = dzOut + (size_t)n * dzOutBS;

#pragma unroll
    for (int sy = 0; sy < 2; ++sy) {
        // 18 float4 mask loads for this sy (channels 4k + 2sy + sx)
        float4 E[18];
#pragma unroll
        for (int k = 0; k < 9; ++k) {
            E[2 * k]     = *(const float4*)(mb + (size_t)(4 * k + 2 * sy) * HWm);
            E[2 * k + 1] = *(const float4*)(mb + (size_t)(4 * k + 2 * sy + 1) * HWm);
        }
#pragma unroll
        for (int j = 0; j < 18; ++j) {
            E[j].x = __expf(E[j].x); E[j].y = __expf(E[j].y);
            E[j].z = __expf(E[j].z); E[j].w = __expf(E[j].w);
        }

        float sm_[4][2], ax_[4][2], ay_[4][2], az_[4][2];
#pragma unroll
        for (int i = 0; i < 4; ++i)
#pragma unroll
            for (int sx = 0; sx < 2; ++sx) {
                sm_[i][sx] = 0.f; ax_[i][sx] = 0.f;
                ay_[i][sx] = 0.f; az_[i][sx] = 0.f;
            }

#pragma unroll
        for (int kh = 0; kh < 3; ++kh) {
            int r = py + kh;
            float4 X0 = *(const float4*)&smx[r][4 * u];
            float4 X1 = *(const float4*)&smx[r][4 * u + 4];
            float4 Y0 = *(const float4*)&smy[r][4 * u];
            float4 Y1 = *(const float4*)&smy[r][4 * u + 4];
            float4 Z0 = *(const float4*)&smz[r][4 * u];
            float4 Z1 = *(const float4*)&smz[r][4 * u + 4];
#pragma unroll
            for (int kw = 0; kw < 3; ++kw) {
                int k = kh * 3 + kw;
#pragma unroll
                for (int i = 0; i < 4; ++i) {
                    int o = 1 + i + kw;   // tap col within [4u .. 4u+7]
                    float txv = (o < 4) ? f4get(X0, o) : f4get(X1, o - 4);
                    float tyv = (o < 4) ? f4get(Y0, o) : f4get(Y1, o - 4);
                    float tzv = (o < 4) ? f4get(Z0, o) : f4get(Z1, o - 4);
#pragma unroll
                    for (int sx = 0; sx < 2; ++sx) {
                        float w = f4get(E[2 * k + sx], i);
                        sm_[i][sx] += w;
                        ax_[i][sx] += w * txv;
                        ay_[i][sx] += w * tyv;
                        az_[i][sx] += w * tzv;
                    }
                }
            }
        }

        // finalize + store: fine row 2*pmy+sy, cols 2*(m0x+4u) + [0..8)
        float rx[8], ry[8], rz[8];
#pragma unroll
        for (int i = 0; i < 4; ++i)
#pragma unroll
            for (int sx = 0; sx < 2; ++sx) {
                float inv = __builtin_amdgcn_rcpf(sm_[i][sx]);
                float fs = 2.0f * inv;   // per-stage flow premul
                rx[2 * i + sx] = ax_[i][sx] * fs;
                ry[2 * i + sx] = ay_[i][sx] * fs;
                rz[2 * i + sx] = az_[i][sx] * inv;
            }
        size_t ro = (size_t)(2 * pmy + sy) * W4 + 2 * (m0x + 4 * u);
        *(float4*)(fo0 + ro)     = make_float4(rx[0], rx[1], rx[2], rx[3]);
        *(float4*)(fo0 + ro + 4) = make_float4(rx[4], rx[5], rx[6], rx[7]);
        *(float4*)(fo1 + ro)     = make_float4(ry[0], ry[1], ry[2], ry[3]);
        *(float4*)(fo1 + ro + 4) = make_float4(ry[4], ry[5], ry[6], ry[7]);
        *(float4*)(dzo + ro)     = make_float4(rz[0], rz[1], rz[2], rz[3]);
        *(float4*)(dzo + ro + 4) = make_float4(rz[4], rz[5], rz[6], rz[7]);
    }
}

extern "C" void kernel_launch(void* const* d_in, const int* in_sizes, int n_in,
                              void* d_out, int out_size, void* d_ws, size_t ws_size,
                              hipStream_t stream) {
    const float* flow16 = (const float*)d_in[0];  // (4,2,48,64)
    const float* dz16   = (const float*)d_in[1];  // (4,1,48,64)
    const float* mask16 = (const float*)d_in[2];  // (4,36,48,64)
    const float* mask8  = (const float*)d_in[3];  // (4,36,96,128)
    const float* mask4  = (const float*)d_in[4];  // (4,36,192,256)
    const float* mask2  = (const float*)d_in[5];  // (4,36,384,512)

    float* ws = (float*)d_ws;
    float* flowB = ws;                            // (4,2,192,256)
    float* dzB   = flowB + 4 * 2 * 192 * 256;     // (4,1,192,256)

    float* out = (float*)d_out;                   // (4,3,768,1024)
    const int HW1 = 768 * 1024;
    const int HW4 = 192 * 256;

    // K1: x16 -> x4. mid = 96x128, tile 8x32 -> 12*4*4 = 192 blocks of 64.
    hipLaunchKernelGGL((fused_up4<48, 64, 8, 32>),
                       dim3(NB * (96 / 8) * (128 / 32)), dim3(8 * 32 / 4), 0, stream,
                       flow16, dz16, mask16, mask8, flowB, dzB, 2 * HW4, HW4);
    // K2: x4 -> x1. mid = 384x512, tile 8x64 -> 48*8*4 = 1536 blocks of 128.
    hipLaunchKernelGGL((fused_up4<192, 256, 8, 64>),
                       dim3(NB * (384 / 8) * (512 / 64)), dim3(8 * 64 / 4), 0, stream,
                       flowB, dzB, mask4, mask2, out, out + 2 * HW1, 3 * HW1, 3 * HW1);
}

// Round 5
// 218.675 us; speedup vs baseline: 1.0448x; 1.0371x over previous
//
#include <hip/hip_runtime.h>

// Cascaded convex upsampling (SEAFLOW3DP), fused in PAIRS of x2 stages:
//   K1: x16 -> x8 -> x4   (mask16 at coarse, mask8 at mid)  -> ws
//   K2: x4  -> x2 -> x1   (mask4  at coarse, mask2 at mid)  -> d_out
//
// Block = TH x TW MID-level tile, NT = TH*TW/2 threads (2 consecutive mids
// per thread). Wave mask-load shape: 16 lane-groups x float2 = 128B line
// per tile row, 4 rows per wave -> 4 fully-consumed lines in flight PER
// INSTRUCTION; 36 such loads issued up-front per thread (288B/thread).
// Mask loads are NONTEMPORAL: each phase-2 mask element is read exactly
// once chip-wide (no reuse), keep them out of the caches.
//
// Phase 1: one thread per COARSE parent (proven R4 form): 36 mask + 27
//          field lane-contiguous loads, computes 2x2 mid quadrants, scalar
//          LDS writes. Out-of-image parents write 0 (== the zero padding
//          the 2nd unfold needs).
// Phase 2: all 36 nt mask loads -> exp -> per sy: 12 ds_read_b64 taps +
//          144 FMA -> float4 stores (16 lanes x 16B = 256B/row contiguous).
//
// Softmax semantics: zero-padded taps contribute 0 to the numerator but
// keep their weight in the denominator -> zero the TAP, not the weight.
// Flow premul=2 per stage, dz premul=1.

#define NB 4

typedef float f2v __attribute__((ext_vector_type(2)));

__device__ __forceinline__ f2v ntload2(const float* p) {
    return __builtin_nontemporal_load((const f2v*)p);
}

template <int Hc, int Wc, int TH, int TW, int NT>
__global__ __launch_bounds__(NT) void fused_up4(
    const float* __restrict__ flowIn,  // (NB,2,Hc,Wc)
    const float* __restrict__ dzIn,    // (NB,1,Hc,Wc)
    const float* __restrict__ maskA,   // (NB,36,Hc,Wc)
    const float* __restrict__ maskB,   // (NB,36,2Hc,2Wc)
    float* __restrict__ flowOut,       // ch0 at n*flowOutBS, ch1 at +4Hc*4Wc
    float* __restrict__ dzOut,         // at n*dzOutBS
    int flowOutBS, int dzOutBS)
{
    static_assert(NT == TH * TW / 2, "2 mids per thread");
    constexpr int HWc = Hc * Wc;
    constexpr int Hm = 2 * Hc, Wm = 2 * Wc;
    constexpr int HWm = Hm * Wm;
    constexpr int W4 = 4 * Wc;
    constexpr int TBX = Wm / TW, TBY = Hm / TH;
    constexpr int RH = TH + 2, WP = TW + 4;         // local cols used: [0, TW+2)
    constexpr int CH = TH / 2 + 2, CW = TW / 2 + 2; // coarse tile incl. halo
    constexpr int NS = CH * CW;
    constexpr int GX = TW / 2;                      // 2-mid groups per row

    __shared__ float smx[RH][WP], smy[RH][WP], smz[RH][WP];

    int b = blockIdx.x;
    int tX = b % TBX;
    int t2 = b / TBX;
    int tY = t2 % TBY;
    int n  = t2 / TBY;

    int m0y = tY * TH, m0x = tX * TW;          // mid tile origin

    int tid = threadIdx.x;
    int u  = tid % GX;                          // 2-mid x-group
    int py = tid / GX;                          // tile row  [0, TH)
    int pmy = m0y + py;

    // ---- phase 2 loads FIRST: 36 nontemporal float2, max lines in flight ----
    const float* mb = maskB + (size_t)n * 36 * HWm + (size_t)pmy * Wm + (m0x + 2 * u);
    f2v E[36];
#pragma unroll
    for (int c = 0; c < 36; ++c) E[c] = ntload2(mb + (size_t)c * HWm);

    // ---------------- phase 1: one thread per coarse parent ----------------
    const float* fb = flowIn + (size_t)n * 2 * HWc;
    const float* db = dzIn   + (size_t)n * HWc;
    const float* mA = maskA  + (size_t)n * 36 * HWc;
    int cy0 = m0y / 2 - 1, cx0 = m0x / 2 - 1;

#pragma unroll
    for (int it = 0; it < (NS + NT - 1) / NT; ++it) {
        int s = it * NT + tid;
        if (s < NS) {
            int lc = s % CW, lr = s / CW;
            int pcy = cy0 + lr, pcx = cx0 + lc;
            float vx[2][2] = {{0.f, 0.f}, {0.f, 0.f}};
            float vy[2][2] = {{0.f, 0.f}, {0.f, 0.f}};
            float vz[2][2] = {{0.f, 0.f}, {0.f, 0.f}};
            if ((unsigned)pcy < (unsigned)Hc && (unsigned)pcx < (unsigned)Wc) {
                const float* ma = mA + (size_t)pcy * Wc + pcx;
                float e[36];
#pragma unroll
                for (int c = 0; c < 36; ++c) e[c] = ma[(size_t)c * HWc];

                float tx[9], ty[9], tz[9];
#pragma unroll
                for (int kh = 0; kh < 3; ++kh) {
                    int hh = pcy + kh - 1;
                    bool vh = (unsigned)hh < (unsigned)Hc;
                    int hcl = min(max(hh, 0), Hc - 1);
#pragma unroll
                    for (int kw = 0; kw < 3; ++kw) {
                        int ww = pcx + kw - 1;
                        bool v = vh && ((unsigned)ww < (unsigned)Wc);
                        int wcl = min(max(ww, 0), Wc - 1);
                        int o = hcl * Wc + wcl;
                        int k = kh * 3 + kw;
                        float x = fb[o], y = fb[HWc + o], z = db[o];
                        tx[k] = v ? x : 0.f;
                        ty[k] = v ? y : 0.f;
                        tz[k] = v ? z : 0.f;
                    }
                }
#pragma unroll
                for (int c = 0; c < 36; ++c) e[c] = __expf(e[c]);

#pragma unroll
                for (int dy = 0; dy < 2; ++dy)
#pragma unroll
                    for (int dx = 0; dx < 2; ++dx) {
                        int q = dy * 2 + dx;
                        float sum = 0.f, ax = 0.f, ay = 0.f, az = 0.f;
#pragma unroll
                        for (int k = 0; k < 9; ++k) {
                            float w = e[k * 4 + q];
                            sum += w;
                            ax += w * tx[k];
                            ay += w * ty[k];
                            az += w * tz[k];
                        }
                        float inv = __builtin_amdgcn_rcpf(sum);
                        float fs = 2.0f * inv;   // per-stage flow premul
                        vx[dy][dx] = ax * fs;
                        vy[dy][dx] = ay * fs;
                        vz[dy][dx] = az * inv;
                    }
            }
            // scatter 2x2 mids into the padded LDS frame (local = global - m0 + 1)
#pragma unroll
            for (int dy = 0; dy < 2; ++dy) {
                int ar = 2 * lr + dy - 1;
                if (ar >= 0 && ar < RH) {
#pragma unroll
                    for (int dx = 0; dx < 2; ++dx) {
                        int ac = 2 * lc + dx - 1;
                        if (ac >= 0 && ac < TW + 2) {
                            smx[ar][ac] = vx[dy][dx];
                            smy[ar][ac] = vy[dy][dx];
                            smz[ar][ac] = vz[dy][dx];
                        }
                    }
                }
            }
        }
    }

    // exp the prefetched mask while loads drain / before barrier
#pragma unroll
    for (int c = 0; c < 36; ++c) { E[c].x = __expf(E[c].x); E[c].y = __expf(E[c].y); }

    __syncthreads();

    // ------------- phase 2: 2 consecutive mids per thread -------------
    float* fo0 = flowOut + (size_t)n * flowOutBS;
    float* fo1 = fo0 + (size_t)(4 * Hc) * W4;      // channel stride = H1*W1
    float* dzo = dzOut + (size_t)n * dzOutBS;

#pragma unroll
    for (int sy = 0; sy < 2; ++sy) {
        float s_[2][2], ax_[2][2], ay_[2][2], az_[2][2];
#pragma unroll
        for (int j = 0; j < 2; ++j)
#pragma unroll
            for (int sx = 0; sx < 2; ++sx) {
                s_[j][sx] = 0.f; ax_[j][sx] = 0.f;
                ay_[j][sx] = 0.f; az_[j][sx] = 0.f;
            }

#pragma unroll
        for (int kh = 0; kh < 3; ++kh) {
            int r = py + kh;
            // taps: local cols 2u .. 2u+3 (mid j, kw -> col 2u + j + kw)
            f2v X0 = *(const f2v*)&smx[r][2 * u];
            f2v X1 = *(const f2v*)&smx[r][2 * u + 2];
            f2v Y0 = *(const f2v*)&smy[r][2 * u];
            f2v Y1 = *(const f2v*)&smy[r][2 * u + 2];
            f2v Z0 = *(const f2v*)&smz[r][2 * u];
            f2v Z1 = *(const f2v*)&smz[r][2 * u + 2];
            float tpx[4] = {X0.x, X0.y, X1.x, X1.y};
            float tpy[4] = {Y0.x, Y0.y, Y1.x, Y1.y};
            float tpz[4] = {Z0.x, Z0.y, Z1.x, Z1.y};
#pragma unroll
            for (int kw = 0; kw < 3; ++kw) {
                int c = (kh * 3 + kw) * 4 + 2 * sy;
#pragma unroll
                for (int j = 0; j < 2; ++j) {
                    float txv = tpx[j + kw];
                    float tyv = tpy[j + kw];
                    float tzv = tpz[j + kw];
#pragma unroll
                    for (int sx = 0; sx < 2; ++sx) {
                        float w = E[c + sx][j];
                        s_[j][sx]  += w;
                        ax_[j][sx] += w * txv;
                        ay_[j][sx] += w * tyv;
                        az_[j][sx] += w * tzv;
                    }
                }
            }
        }

        float rx[4], ry[4], rz[4];
#pragma unroll
        for (int j = 0; j < 2; ++j)
#pragma unroll
            for (int sx = 0; sx < 2; ++sx) {
                float inv = __builtin_amdgcn_rcpf(s_[j][sx]);
                float fs = 2.0f * inv;   // per-stage flow premul
                rx[2 * j + sx] = ax_[j][sx] * fs;
                ry[2 * j + sx] = ay_[j][sx] * fs;
                rz[2 * j + sx] = az_[j][sx] * inv;
            }
        size_t ro = (size_t)(2 * pmy + sy) * W4 + 2 * m0x + 4 * u;
        *(float4*)(fo0 + ro) = make_float4(rx[0], rx[1], rx[2], rx[3]);
        *(float4*)(fo1 + ro) = make_float4(ry[0], ry[1], ry[2], ry[3]);
        *(float4*)(dzo + ro) = make_float4(rz[0], rz[1], rz[2], rz[3]);
    }
}

extern "C" void kernel_launch(void* const* d_in, const int* in_sizes, int n_in,
                              void* d_out, int out_size, void* d_ws, size_t ws_size,
                              hipStream_t stream) {
    const float* flow16 = (const float*)d_in[0];  // (4,2,48,64)
    const float* dz16   = (const float*)d_in[1];  // (4,1,48,64)
    const float* mask16 = (const float*)d_in[2];  // (4,36,48,64)
    const float* mask8  = (const float*)d_in[3];  // (4,36,96,128)
    const float* mask4  = (const float*)d_in[4];  // (4,36,192,256)
    const float* mask2  = (const float*)d_in[5];  // (4,36,384,512)

    float* ws = (float*)d_ws;
    float* flowB = ws;                            // (4,2,192,256)
    float* dzB   = flowB + 4 * 2 * 192 * 256;     // (4,1,192,256)

    float* out = (float*)d_out;                   // (4,3,768,1024)
    const int HW1 = 768 * 1024;
    const int HW4 = 192 * 256;

    // K1: x16 -> x4. mid = 96x128, tile 8x32 -> 4*12*4 = 192 blocks of 128.
    hipLaunchKernelGGL((fused_up4<48, 64, 8, 32, 128>),
                       dim3(NB * (96 / 8) * (128 / 32)), dim3(128), 0, stream,
                       flow16, dz16, mask16, mask8, flowB, dzB, 2 * HW4, HW4);
    // K2: x4 -> x1. mid = 384x512, tile 8x32 -> 4*48*16 = 3072 blocks of 128.
    hipLaunchKernelGGL((fused_up4<192, 256, 8, 32, 128>),
                       dim3(NB * (384 / 8) * (512 / 32)), dim3(128), 0, stream,
                       flowB, dzB, mask4, mask2, out, out + 2 * HW1, 3 * HW1, 3 * HW1);
}